// Round 6
// baseline (25.130 us; speedup 1.0000x reference)
//
#include <hip/hip_runtime.h>

// out[b,h,w,8*i+j] = x[b,h,w,i] * weight[h,w,j] + bias
// x: (32,112,112,8) f32, weight: (112,112,8) f32, bias: (1,) f32
// out: (32,112,112,64) f32
//
// Thread = (pixel, x-channel i); owns output channels 8i..8i+7 (32B).
// Block (256 thr) = 32 pixels x 8 channels; grid = (392 pixel-groups, 8 batch-groups).
// - x loads: 8 lanes/pixel read 8 contiguous floats -> coalesced, zero redundancy
// - stores: lane-inner i => wave writes one contiguous 2KB span (2x dwordx4/lane)
// - weight: one f32x8 row load per thread, reused across 4 batches
// Plain loads/stores (R3: nontemporal hints regress -15%). B=4 (R5: B=8 regressed).

typedef float f32x8 __attribute__((ext_vector_type(8)));

#define HW_PIX (112 * 112)   // 12544 = 392 * 32
#define PIX_PER_BLK 32
#define B_PER_THREAD 4

__global__ __launch_bounds__(256) void mult_layer_kernel(
    const float* __restrict__ x,
    const float* __restrict__ weight,
    const float* __restrict__ bias,
    float* __restrict__ out) {
  const int tid = threadIdx.x;
  const int i   = tid & 7;           // x channel (inner -> contiguous stores)
  const int p   = tid >> 3;          // pixel within block (0..31)

  const int hw = blockIdx.x * PIX_PER_BLK + p;   // 0..12543
  const int b0 = blockIdx.y * B_PER_THREAD;      // 0,4,...,28

  const f32x8 wv = *reinterpret_cast<const f32x8*>(weight + hw * 8);
  const float bv = bias[0];

  // int32 element offsets (out: 25.7M floats = 3.2M f32x8 -> fits easily)
  const float* xp = x + (b0 * HW_PIX + hw) * 8 + i;
  f32x8* op = reinterpret_cast<f32x8*>(out) + (b0 * HW_PIX + hw) * 8 + i;

  float xv[B_PER_THREAD];
#pragma unroll
  for (int bb = 0; bb < B_PER_THREAD; ++bb)
    xv[bb] = xp[bb * HW_PIX * 8];

#pragma unroll
  for (int bb = 0; bb < B_PER_THREAD; ++bb) {
    f32x8 o;
#pragma unroll
    for (int j = 0; j < 8; ++j)
      o[j] = fmaf(xv[bb], wv[j], bv);
    op[bb * HW_PIX * 8] = o;
  }
}

extern "C" void kernel_launch(void* const* d_in, const int* in_sizes, int n_in,
                              void* d_out, int out_size, void* d_ws, size_t ws_size,
                              hipStream_t stream) {
  const float* x      = (const float*)d_in[0];
  const float* weight = (const float*)d_in[1];
  const float* bias   = (const float*)d_in[2];
  float* out          = (float*)d_out;

  dim3 grid(HW_PIX / PIX_PER_BLK, 32 / B_PER_THREAD, 1);   // (392, 8)
  dim3 block(256, 1, 1);
  mult_layer_kernel<<<grid, block, 0, stream>>>(x, weight, bias, out);
}

// Round 7
// 23.737 us; speedup vs baseline: 1.0587x; 1.0587x over previous
//
#include <hip/hip_runtime.h>

// out[b,h,w,8*i+j] = x[b,h,w,i] * weight[h,w,j] + bias
// x: (32,112,112,8) f32, weight: (112,112,8) f32, bias: (1,) f32
// out: (32,112,112,64) f32
//
// R4 mapping (best, 22.9us): thread -> one output float4 per batch, B=4 batches.
// 16B/lane, lane-contiguous stores: wave writes 1KB dense (R6: 32B/lane = holes, -10%).
// Block = 512 thr = 32 pixels -> 8KB contiguous per block; grid (392, 8) = 3136 blocks.
// weight float4 loaded once per thread, reused x4 batches; int32 offsets.
// Plain loads/stores (R3: nontemporal regresses -15%).

typedef float f32x4 __attribute__((ext_vector_type(4)));

#define HW_PIX (112 * 112)   // 12544 = 392 * 32
#define PIX_PER_BLK 32       // 512 threads / 16 subs
#define B_PER_THREAD 4

__global__ __launch_bounds__(512) void mult_layer_kernel(
    const float* __restrict__ x,
    const float* __restrict__ weight,
    const float* __restrict__ bias,
    float* __restrict__ out) {
  const int tid = threadIdx.x;
  const int p   = tid >> 4;          // pixel within block (0..31)
  const int sub = tid & 15;          // float4 index within 64 channels
  const int i   = sub >> 1;          // x channel (0..7)
  const int j0  = (sub & 1) << 2;    // weight channel base (0 or 4)

  const int hw = blockIdx.x * PIX_PER_BLK + p;        // 0..12543
  const int b0 = blockIdx.y * B_PER_THREAD;           // 0,4,...,28

  const f32x4 wv = *reinterpret_cast<const f32x4*>(weight + hw * 8 + j0);
  const float bv = bias[0];

  const float* xp = x + (b0 * HW_PIX + hw) * 8 + i;
  f32x4* op = reinterpret_cast<f32x4*>(out) + (b0 * HW_PIX + hw) * 16 + sub;

  float xv[B_PER_THREAD];
#pragma unroll
  for (int bb = 0; bb < B_PER_THREAD; ++bb)
    xv[bb] = xp[bb * HW_PIX * 8];

#pragma unroll
  for (int bb = 0; bb < B_PER_THREAD; ++bb) {
    f32x4 o;
    o.x = fmaf(xv[bb], wv.x, bv);
    o.y = fmaf(xv[bb], wv.y, bv);
    o.z = fmaf(xv[bb], wv.z, bv);
    o.w = fmaf(xv[bb], wv.w, bv);
    op[bb * HW_PIX * 16] = o;
  }
}

extern "C" void kernel_launch(void* const* d_in, const int* in_sizes, int n_in,
                              void* d_out, int out_size, void* d_ws, size_t ws_size,
                              hipStream_t stream) {
  const float* x      = (const float*)d_in[0];
  const float* weight = (const float*)d_in[1];
  const float* bias   = (const float*)d_in[2];
  float* out          = (float*)d_out;

  dim3 grid(HW_PIX / PIX_PER_BLK, 32 / B_PER_THREAD, 1);   // (392, 8)
  dim3 block(512, 1, 1);
  mult_layer_kernel<<<grid, block, 0, stream>>>(x, weight, bias, out);
}